// Round 1
// baseline (846.485 us; speedup 1.0000x reference)
//
#include <hip/hip_runtime.h>

#define SEQ 16384
#define DIM 1280
#define NH 16
#define HD 80
#define NSEG 16
#define SEGL 1024

typedef __attribute__((ext_vector_type(8))) short bf16x8;
typedef __attribute__((ext_vector_type(4))) float f32x4;

__device__ inline unsigned short f2bf(float f){
  unsigned int x = __builtin_bit_cast(unsigned int, f);
  unsigned int r = (x + 0x7FFFu + ((x >> 16) & 1u)) >> 16;
  return (unsigned short)r;
}
__device__ inline float bf2f(unsigned short u){
  unsigned int x = ((unsigned int)u) << 16;
  return __builtin_bit_cast(float, x);
}

__device__ inline void gload16(const unsigned short* g, unsigned short* l){
  __builtin_amdgcn_global_load_lds((const __attribute__((address_space(1))) void*)g,
                                   (__attribute__((address_space(3))) void*)l, 16, 0, 0);
}

// ---------------- pack f32 -> bf16 ----------------
__global__ __launch_bounds__(256) void pack_bf16_kernel(const float* __restrict__ src,
                                                        unsigned short* __restrict__ dst, int n4){
  int i = blockIdx.x * 256 + threadIdx.x;
  if (i >= n4) return;
  float4 v = ((const float4*)src)[i];
  ushort4 o;
  o.x = f2bf(v.x); o.y = f2bf(v.y); o.z = f2bf(v.z); o.w = f2bf(v.w);
  ((ushort4*)dst)[i] = o;
}

// ---------------- GEMM C = A * B^T (+bias), bf16 in, m97-style 128x128 tile ----------------
// EPI==0: scatter bf16 into QKV[3][NH][SEQ][HD]  (N == 3*DIM)
// EPI==1: write f32 row-major [M][N]
template<int EPI>
__global__ __launch_bounds__(256) void gemm_bt_kernel(const unsigned short* __restrict__ A,
    const unsigned short* __restrict__ B, const float* __restrict__ bias,
    void* __restrict__ Cout, int M, int N, int K){
  __shared__ __attribute__((aligned(16))) unsigned short Asm[128*32];
  __shared__ __attribute__((aligned(16))) unsigned short Bsm[128*32];
  int ntiles = N >> 7;
  int bx = blockIdx.x;
  int tm = (bx / ntiles) << 7;
  int tn = (bx % ntiles) << 7;
  int tid = threadIdx.x, wid = tid >> 6, l = tid & 63;
  int lr = l & 15, lh = l >> 4;
  int wr = (wid >> 1) << 6, wc = (wid & 1) << 6;
  int lrow = l >> 2, lk = (l & 3) * 8;
  f32x4 zf = {0.f,0.f,0.f,0.f};
  f32x4 acc[4][4];
  #pragma unroll
  for (int i=0;i<4;i++)
    #pragma unroll
    for (int j=0;j<4;j++) acc[i][j] = zf;
  const unsigned short* Ab = A + (size_t)tm * K;
  const unsigned short* Bb = B + (size_t)tn * K;
  for (int kt = 0; kt < K; kt += 32){
    __syncthreads();
    #pragma unroll
    for (int i=0;i<2;i++){
      int ch = wid*2 + i;
      gload16(Ab + (size_t)(ch*16 + lrow)*K + kt + lk, &Asm[ch*16*32]);
      gload16(Bb + (size_t)(ch*16 + lrow)*K + kt + lk, &Bsm[ch*16*32]);
    }
    __syncthreads();
    bf16x8 af[4], bfr[4];
    #pragma unroll
    for (int mi=0;mi<4;mi++) af[mi] = *(const bf16x8*)&Asm[(wr + mi*16 + lr)*32 + lh*8];
    #pragma unroll
    for (int ni=0;ni<4;ni++) bfr[ni] = *(const bf16x8*)&Bsm[(wc + ni*16 + lr)*32 + lh*8];
    #pragma unroll
    for (int mi=0;mi<4;mi++)
      #pragma unroll
      for (int ni=0;ni<4;ni++)
        acc[mi][ni] = __builtin_amdgcn_mfma_f32_16x16x32_bf16(af[mi], bfr[ni], acc[mi][ni], 0,0,0);
  }
  // epilogue
  #pragma unroll
  for (int ni=0;ni<4;ni++){
    int col = tn + wc + ni*16 + lr;
    float bv = bias[col];
    if (EPI == 0){
      unsigned short* Q = (unsigned short*)Cout;
      int which = col / DIM;
      int rem = col - which*DIM;
      int hh = rem / HD;
      int d = rem - hh*HD;
      size_t base = (size_t)(which*NH + hh) * SEQ;
      #pragma unroll
      for (int mi=0;mi<4;mi++){
        #pragma unroll
        for (int r=0;r<4;r++){
          int row = tm + wr + mi*16 + lh*4 + r;
          Q[(base + row)*HD + d] = f2bf(acc[mi][ni][r] + bv);
        }
      }
    } else {
      float* C = (float*)Cout;
      #pragma unroll
      for (int mi=0;mi<4;mi++){
        #pragma unroll
        for (int r=0;r<4;r++){
          int row = tm + wr + mi*16 + lh*4 + r;
          C[(size_t)row*N + col] = acc[mi][ni][r] + bv;
        }
      }
    }
  }
}

// ---------------- in-place RoPE on Q,K parts of QKV ----------------
__global__ __launch_bounds__(256) void rope_kernel(unsigned short* __restrict__ QKV,
    const float* __restrict__ cosb, const float* __restrict__ sinb){
  unsigned int gid = blockIdx.x * 256 + threadIdx.x; // 2*NH*SEQ*40 total
  int pd = gid % 40;
  unsigned int row = gid / 40;       // [(which*NH+h)*SEQ + s]
  int s = row % SEQ;
  unsigned short* p = QKV + (size_t)row * HD;
  float c  = cosb[s*HD + pd];
  float sn = sinb[s*HD + pd];
  float x1 = bf2f(p[pd]);
  float x2 = bf2f(p[pd+40]);
  p[pd]    = f2bf(x1*c - x2*sn);
  p[pd+40] = f2bf(x2*c + x1*sn);
}

// ---------------- flash attention: block = (seg, head, 64 q-rows), 4 waves x 16 rows ----------------
__global__ __launch_bounds__(256) void attn_kernel(const unsigned short* __restrict__ QKV,
                                                   unsigned short* __restrict__ AO){
  int bid = blockIdx.x;
  int qt  = bid & 15;
  int h   = (bid >> 4) & 15;
  int seg = bid >> 8;
  int tid = threadIdx.x, wid = tid >> 6, l = tid & 63;
  int lr = l & 15, lh = l >> 4;
  const unsigned short* Qb = QKV + (size_t)(0*NH + h) * SEQ * HD;
  const unsigned short* Kb = QKV + (size_t)(1*NH + h) * SEQ * HD;
  const unsigned short* Vb = QKV + (size_t)(2*NH + h) * SEQ * HD;
  int q0 = seg*SEGL + qt*64;
  __shared__ __attribute__((aligned(16))) unsigned short Ksm[64*104];
  __shared__ __attribute__((aligned(16))) unsigned short Vtsm[80*72];
  __shared__ __attribute__((aligned(16))) unsigned short Psm[4][16*72];
  bf16x8 qf[3];
  {
    const unsigned short* qp = Qb + (size_t)(q0 + wid*16 + lr) * HD;
    #pragma unroll
    for (int c=0;c<3;c++){
      int d0 = c*32 + lh*8;
      bf16x8 z = {0,0,0,0,0,0,0,0};
      qf[c] = (d0 < HD) ? *(const bf16x8*)(qp + d0) : z;
    }
  }
  f32x4 zf = {0.f,0.f,0.f,0.f};
  f32x4 o[5];
  #pragma unroll
  for (int dt=0;dt<5;dt++) o[dt] = zf;
  float m[4], lsum[4];
  #pragma unroll
  for (int r=0;r<4;r++){ m[r] = -1e30f; lsum[r] = 0.f; }
  const float SCALE = 0.111803398874989485f; // 1/sqrt(80)
  for (int kt=0; kt<16; kt++){
    int k0 = seg*SEGL + kt*64;
    // stage K tile [64][104] (d 80..95 zeroed for padded MFMA chunk)
    #pragma unroll
    for (int i=0;i<3;i++){
      int u = tid + 256*i;      // 768 units
      int row = u / 12, c = u % 12;
      uint4 val = {0,0,0,0};
      if (c < 10) val = *(const uint4*)(Kb + (size_t)(k0+row)*HD + c*8);
      *(uint4*)&Ksm[row*104 + c*8] = val;
    }
    // stage V transposed [80][72]
    #pragma unroll
    for (int i=0;i<3;i++){
      int u = tid + 256*i;
      if (u < 640){
        int key = u / 10, c = u % 10;
        union { uint4 u4; unsigned short s[8]; } tv;
        tv.u4 = *(const uint4*)(Vb + (size_t)(k0+key)*HD + c*8);
        #pragma unroll
        for (int j=0;j<8;j++) Vtsm[(c*8+j)*72 + key] = tv.s[j];
      }
    }
    __syncthreads();
    // QK^T
    f32x4 s[4];
    #pragma unroll
    for (int n=0;n<4;n++) s[n] = zf;
    #pragma unroll
    for (int c=0;c<3;c++){
      #pragma unroll
      for (int n=0;n<4;n++){
        bf16x8 kf = *(const bf16x8*)&Ksm[(n*16+lr)*104 + c*32 + lh*8];
        s[n] = __builtin_amdgcn_mfma_f32_16x16x32_bf16(qf[c], kf, s[n], 0,0,0);
      }
    }
    #pragma unroll
    for (int n=0;n<4;n++) s[n] *= SCALE;
    // online softmax (row = lh*4+r, cols spread over lanes lr and n)
    float mt[4];
    #pragma unroll
    for (int r=0;r<4;r++)
      mt[r] = fmaxf(fmaxf(s[0][r], s[1][r]), fmaxf(s[2][r], s[3][r]));
    #pragma unroll
    for (int off=1; off<16; off<<=1)
      #pragma unroll
      for (int r=0;r<4;r++) mt[r] = fmaxf(mt[r], __shfl_xor(mt[r], off));
    float corr[4];
    #pragma unroll
    for (int r=0;r<4;r++){
      float mn = fmaxf(m[r], mt[r]);
      corr[r] = __expf(m[r] - mn);
      m[r] = mn;
    }
    float rs[4] = {0.f,0.f,0.f,0.f};
    #pragma unroll
    for (int n=0;n<4;n++)
      #pragma unroll
      for (int r=0;r<4;r++){
        float p = __expf(s[n][r] - m[r]);
        s[n][r] = p;
        rs[r] += p;
      }
    #pragma unroll
    for (int off=1; off<16; off<<=1)
      #pragma unroll
      for (int r=0;r<4;r++) rs[r] += __shfl_xor(rs[r], off);
    #pragma unroll
    for (int r=0;r<4;r++) lsum[r] = lsum[r]*corr[r] + rs[r];
    #pragma unroll
    for (int dt=0;dt<5;dt++)
      #pragma unroll
      for (int r=0;r<4;r++) o[dt][r] *= corr[r];
    // P -> LDS (wave-private), transpose to A-frag layout
    #pragma unroll
    for (int n=0;n<4;n++)
      #pragma unroll
      for (int r=0;r<4;r++)
        Psm[wid][(lh*4+r)*72 + n*16 + lr] = f2bf(s[n][r]);
    // PV
    #pragma unroll
    for (int c=0;c<2;c++){
      bf16x8 pf = *(const bf16x8*)&Psm[wid][lr*72 + c*32 + lh*8];
      #pragma unroll
      for (int dt=0;dt<5;dt++){
        bf16x8 vf = *(const bf16x8*)&Vtsm[(dt*16+lr)*72 + c*32 + lh*8];
        o[dt] = __builtin_amdgcn_mfma_f32_16x16x32_bf16(pf, vf, o[dt], 0,0,0);
      }
    }
    __syncthreads();
  }
  // epilogue: divide by row sum, write bf16 AO[S][DIM]
  #pragma unroll
  for (int r=0;r<4;r++){
    float inv = 1.0f / lsum[r];
    int qrow = q0 + wid*16 + lh*4 + r;
    #pragma unroll
    for (int dt=0;dt<5;dt++)
      AO[(size_t)qrow*DIM + h*HD + dt*16 + lr] = f2bf(o[dt][r]*inv);
  }
}

extern "C" void kernel_launch(void* const* d_in, const int* in_sizes, int n_in,
                              void* d_out, int out_size, void* d_ws, size_t ws_size,
                              hipStream_t stream){
  const float* hs    = (const float*)d_in[0];
  const float* cosb  = (const float*)d_in[1];
  const float* sinb  = (const float*)d_in[2];
  const float* wqkv  = (const float*)d_in[3];
  const float* bqkv  = (const float*)d_in[4];
  const float* wproj = (const float*)d_in[5];
  const float* bproj = (const float*)d_in[6];
  float* out = (float*)d_out;

  unsigned short* Abf    = (unsigned short*)d_ws;              // [SEQ][DIM] bf16
  unsigned short* Wqkvb  = Abf + (size_t)SEQ*DIM;              // [3*DIM][DIM] bf16
  unsigned short* Wprojb = Wqkvb + (size_t)3*DIM*DIM;          // [DIM][DIM] bf16
  unsigned short* QKVb   = Wprojb + (size_t)DIM*DIM;           // [3][NH][SEQ][HD] bf16
  unsigned short* AObf   = Abf;                                // reuse (A dead after gemm1)

  pack_bf16_kernel<<<(SEQ*DIM/4)/256, 256, 0, stream>>>(hs, Abf, SEQ*DIM/4);
  pack_bf16_kernel<<<(3*DIM*DIM/4)/256, 256, 0, stream>>>(wqkv, Wqkvb, 3*DIM*DIM/4);
  pack_bf16_kernel<<<(DIM*DIM/4)/256, 256, 0, stream>>>(wproj, Wprojb, DIM*DIM/4);

  gemm_bt_kernel<0><<<(SEQ/128)*((3*DIM)/128), 256, 0, stream>>>(Abf, Wqkvb, bqkv,
                                                                 (void*)QKVb, SEQ, 3*DIM, DIM);

  rope_kernel<<<(2*NH*SEQ*40)/256, 256, 0, stream>>>(QKVb, cosb, sinb);

  attn_kernel<<<NSEG*NH*(SEGL/64), 256, 0, stream>>>(QKVb, AObf);

  gemm_bt_kernel<1><<<(SEQ/128)*(DIM/128), 256, 0, stream>>>(AObf, Wprojb, bproj,
                                                             (void*)out, SEQ, DIM, DIM);
}

// Round 2
// 749.562 us; speedup vs baseline: 1.1293x; 1.1293x over previous
//
#include <hip/hip_runtime.h>

#define SEQ 16384
#define DIM 1280
#define NH 16
#define HD 80
#define NSEG 16
#define SEGL 1024

typedef __attribute__((ext_vector_type(8))) short bf16x8;
typedef __attribute__((ext_vector_type(4))) float f32x4;

__device__ inline unsigned short f2bf(float f){
  unsigned int x = __builtin_bit_cast(unsigned int, f);
  unsigned int r = (x + 0x7FFFu + ((x >> 16) & 1u)) >> 16;
  return (unsigned short)r;
}
__device__ inline float bf2f(unsigned short u){
  unsigned int x = ((unsigned int)u) << 16;
  return __builtin_bit_cast(float, x);
}

__device__ inline void gload16(const unsigned short* g, unsigned short* l){
  __builtin_amdgcn_global_load_lds((const __attribute__((address_space(1))) void*)g,
                                   (__attribute__((address_space(3))) void*)l, 16, 0, 0);
}

// ---------------- pack f32 -> bf16 ----------------
__global__ __launch_bounds__(256) void pack_bf16_kernel(const float* __restrict__ src,
                                                        unsigned short* __restrict__ dst, int n4){
  int i = blockIdx.x * 256 + threadIdx.x;
  if (i >= n4) return;
  float4 v = ((const float4*)src)[i];
  ushort4 o;
  o.x = f2bf(v.x); o.y = f2bf(v.y); o.z = f2bf(v.z); o.w = f2bf(v.w);
  ((ushort4*)dst)[i] = o;
}

// ---------------- GEMM C = A * B^T (+bias), bf16 in, m97-style 128x128 tile ----------------
// EPI==0: scatter bf16 into QKV[3][NH][SEQ][HD]  (N == 3*DIM)
// EPI==1: write f32 row-major [M][N]
template<int EPI>
__global__ __launch_bounds__(256) void gemm_bt_kernel(const unsigned short* __restrict__ A,
    const unsigned short* __restrict__ B, const float* __restrict__ bias,
    void* __restrict__ Cout, int M, int N, int K){
  __shared__ __attribute__((aligned(16))) unsigned short Asm[128*32];
  __shared__ __attribute__((aligned(16))) unsigned short Bsm[128*32];
  int ntiles = N >> 7;
  int bx = blockIdx.x;
  int tm = (bx / ntiles) << 7;
  int tn = (bx % ntiles) << 7;
  int tid = threadIdx.x, wid = tid >> 6, l = tid & 63;
  int lr = l & 15, lh = l >> 4;
  int wr = (wid >> 1) << 6, wc = (wid & 1) << 6;
  int lrow = l >> 2, lk = (l & 3) * 8;
  f32x4 zf = {0.f,0.f,0.f,0.f};
  f32x4 acc[4][4];
  #pragma unroll
  for (int i=0;i<4;i++)
    #pragma unroll
    for (int j=0;j<4;j++) acc[i][j] = zf;
  const unsigned short* Ab = A + (size_t)tm * K;
  const unsigned short* Bb = B + (size_t)tn * K;
  for (int kt = 0; kt < K; kt += 32){
    __syncthreads();
    #pragma unroll
    for (int i=0;i<2;i++){
      int ch = wid*2 + i;
      gload16(Ab + (size_t)(ch*16 + lrow)*K + kt + lk, &Asm[ch*16*32]);
      gload16(Bb + (size_t)(ch*16 + lrow)*K + kt + lk, &Bsm[ch*16*32]);
    }
    __syncthreads();
    bf16x8 af[4], bfr[4];
    #pragma unroll
    for (int mi=0;mi<4;mi++) af[mi] = *(const bf16x8*)&Asm[(wr + mi*16 + lr)*32 + lh*8];
    #pragma unroll
    for (int ni=0;ni<4;ni++) bfr[ni] = *(const bf16x8*)&Bsm[(wc + ni*16 + lr)*32 + lh*8];
    #pragma unroll
    for (int mi=0;mi<4;mi++)
      #pragma unroll
      for (int ni=0;ni<4;ni++)
        acc[mi][ni] = __builtin_amdgcn_mfma_f32_16x16x32_bf16(af[mi], bfr[ni], acc[mi][ni], 0,0,0);
  }
  // epilogue
  #pragma unroll
  for (int ni=0;ni<4;ni++){
    int col = tn + wc + ni*16 + lr;
    float bv = bias[col];
    if (EPI == 0){
      unsigned short* Q = (unsigned short*)Cout;
      int which = col / DIM;
      int rem = col - which*DIM;
      int hh = rem / HD;
      int d = rem - hh*HD;
      size_t base = (size_t)(which*NH + hh) * SEQ;
      #pragma unroll
      for (int mi=0;mi<4;mi++){
        #pragma unroll
        for (int r=0;r<4;r++){
          int row = tm + wr + mi*16 + lh*4 + r;
          Q[(base + row)*HD + d] = f2bf(acc[mi][ni][r] + bv);
        }
      }
    } else {
      float* C = (float*)Cout;
      #pragma unroll
      for (int mi=0;mi<4;mi++){
        #pragma unroll
        for (int r=0;r<4;r++){
          int row = tm + wr + mi*16 + lh*4 + r;
          C[(size_t)row*N + col] = acc[mi][ni][r] + bv;
        }
      }
    }
  }
}

// ---------------- in-place RoPE on Q,K parts of QKV ----------------
__global__ __launch_bounds__(256) void rope_kernel(unsigned short* __restrict__ QKV,
    const float* __restrict__ cosb, const float* __restrict__ sinb){
  unsigned int gid = blockIdx.x * 256 + threadIdx.x; // 2*NH*SEQ*40 total
  int pd = gid % 40;
  unsigned int row = gid / 40;       // [(which*NH+h)*SEQ + s]
  int s = row % SEQ;
  unsigned short* p = QKV + (size_t)row * HD;
  float c  = cosb[s*HD + pd];
  float sn = sinb[s*HD + pd];
  float x1 = bf2f(p[pd]);
  float x2 = bf2f(p[pd+40]);
  p[pd]    = f2bf(x1*c - x2*sn);
  p[pd+40] = f2bf(x2*c + x1*sn);
}

// ---------------- transpose V: [NH][SEQ][HD] -> Vt [NH][HD][SEQ] ----------------
__global__ __launch_bounds__(256) void transpose_v_kernel(const unsigned short* __restrict__ V,
                                                          unsigned short* __restrict__ Vt){
  __shared__ unsigned short L[64*84];
  int bid = blockIdx.x;
  int h  = bid >> 8;           // SEQ/64 = 256 s-tiles
  int st = bid & 255;
  int s0 = st * 64;
  int tid = threadIdx.x;
  const unsigned short* Vs = V + (size_t)h * SEQ * HD;
  // read phase: 64 rows x 80 d, coalesced uint4
  #pragma unroll
  for (int i=0;i<3;i++){
    int u = i*256 + tid;
    if (u < 640){
      int r = u / 10, c = u % 10;
      uint4 v = *(const uint4*)(Vs + (size_t)(s0 + r)*HD + c*8);
      unsigned int* p = (unsigned int*)&L[r*84 + c*8];
      p[0] = v.x; p[1] = v.y; p[2] = v.z; p[3] = v.w;
    }
  }
  __syncthreads();
  // write phase: 80 d-rows x 64 s, pack 4 shorts per uint2
  unsigned short* Vd = Vt + (size_t)h * HD * SEQ;
  #pragma unroll
  for (int i=0;i<5;i++){
    int u = i*256 + tid;      // 1280 units
    int d = u >> 4, g = u & 15;
    int sb = g*4;
    unsigned int w0 = (unsigned int)L[(sb+0)*84 + d] | ((unsigned int)L[(sb+1)*84 + d] << 16);
    unsigned int w1 = (unsigned int)L[(sb+2)*84 + d] | ((unsigned int)L[(sb+3)*84 + d] << 16);
    uint2 o = {w0, w1};
    *(uint2*)(Vd + (size_t)d*SEQ + s0 + sb) = o;
  }
}

// ---------------- flash attention: block = (seg, head, 64 q-rows), 4 waves x 16 rows ----------------
__global__ __launch_bounds__(256) void attn_kernel(const unsigned short* __restrict__ QKV,
                                                   const unsigned short* __restrict__ Vt,
                                                   unsigned short* __restrict__ AO){
  int bid = blockIdx.x;
  int qt  = bid & 15;
  int h   = (bid >> 4) & 15;
  int seg = bid >> 8;
  int tid = threadIdx.x, wid = tid >> 6, l = tid & 63;
  int lr = l & 15, lh = l >> 4;
  const unsigned short* Qb = QKV + (size_t)(0*NH + h) * SEQ * HD;
  const unsigned short* Kb = QKV + (size_t)(1*NH + h) * SEQ * HD;
  const unsigned short* Vtb = Vt + (size_t)h * HD * SEQ;
  int q0 = seg*SEGL + qt*64;
  __shared__ __attribute__((aligned(16))) unsigned short Ksm[64*104];
  __shared__ __attribute__((aligned(16))) unsigned short Vtsm[80*72];
  __shared__ __attribute__((aligned(16))) unsigned short Psm[4][16*72];
  bf16x8 qf[3];
  {
    const unsigned short* qp = Qb + (size_t)(q0 + wid*16 + lr) * HD;
    #pragma unroll
    for (int c=0;c<3;c++){
      int d0 = c*32 + lh*8;
      bf16x8 z = {0,0,0,0,0,0,0,0};
      qf[c] = (d0 < HD) ? *(const bf16x8*)(qp + d0) : z;
    }
  }
  f32x4 zf = {0.f,0.f,0.f,0.f};
  f32x4 o[5];
  #pragma unroll
  for (int dt=0;dt<5;dt++) o[dt] = zf;
  float m[4], lsum[4];
  #pragma unroll
  for (int r=0;r<4;r++){ m[r] = -1e30f; lsum[r] = 0.f; }
  // fold 1/sqrt(80) * log2(e) so softmax uses exp2 directly
  const float SCL2E = 0.111803398874989485f * 1.4426950408889634f;
  for (int kt=0; kt<16; kt++){
    int k0 = seg*SEGL + kt*64;
    // stage K tile [64][104] (d 80..95 zeroed for padded MFMA chunk)
    #pragma unroll
    for (int i=0;i<3;i++){
      int u = tid + 256*i;      // 768 units
      int row = u / 12, c = u % 12;
      uint4 val = {0,0,0,0};
      if (c < 10) val = *(const uint4*)(Kb + (size_t)(k0+row)*HD + c*8);
      *(uint4*)&Ksm[row*104 + c*8] = val;
    }
    // stage V^T tile [80][72] -- straight vectorized copy from Vt global
    #pragma unroll
    for (int i=0;i<3;i++){
      int u = tid + 256*i;      // 640 units
      if (u < 640){
        int d = u >> 3, c = u & 7;
        uint4 v = *(const uint4*)(Vtb + (size_t)d*SEQ + k0 + c*8);
        *(uint4*)&Vtsm[d*72 + c*8] = v;
      }
    }
    __syncthreads();
    // QK^T (scores scaled into log2 domain)
    f32x4 s[4];
    #pragma unroll
    for (int n=0;n<4;n++) s[n] = zf;
    #pragma unroll
    for (int c=0;c<3;c++){
      #pragma unroll
      for (int n=0;n<4;n++){
        bf16x8 kf = *(const bf16x8*)&Ksm[(n*16+lr)*104 + c*32 + lh*8];
        s[n] = __builtin_amdgcn_mfma_f32_16x16x32_bf16(qf[c], kf, s[n], 0,0,0);
      }
    }
    #pragma unroll
    for (int n=0;n<4;n++) s[n] *= SCL2E;
    // online softmax in base-2 (row = lh*4+r, cols spread over lanes lr and n)
    float mt[4];
    #pragma unroll
    for (int r=0;r<4;r++)
      mt[r] = fmaxf(fmaxf(s[0][r], s[1][r]), fmaxf(s[2][r], s[3][r]));
    #pragma unroll
    for (int off=1; off<16; off<<=1)
      #pragma unroll
      for (int r=0;r<4;r++) mt[r] = fmaxf(mt[r], __shfl_xor(mt[r], off));
    float corr[4];
    #pragma unroll
    for (int r=0;r<4;r++){
      float mn = fmaxf(m[r], mt[r]);
      corr[r] = exp2f(m[r] - mn);
      m[r] = mn;
    }
    float rs[4] = {0.f,0.f,0.f,0.f};
    #pragma unroll
    for (int n=0;n<4;n++)
      #pragma unroll
      for (int r=0;r<4;r++){
        float p = exp2f(s[n][r] - m[r]);
        s[n][r] = p;
        rs[r] += p;
      }
    #pragma unroll
    for (int off=1; off<16; off<<=1)
      #pragma unroll
      for (int r=0;r<4;r++) rs[r] += __shfl_xor(rs[r], off);
    #pragma unroll
    for (int r=0;r<4;r++) lsum[r] = lsum[r]*corr[r] + rs[r];
    #pragma unroll
    for (int dt=0;dt<5;dt++)
      #pragma unroll
      for (int r=0;r<4;r++) o[dt][r] *= corr[r];
    // P -> LDS (wave-private), transpose to A-frag layout
    #pragma unroll
    for (int n=0;n<4;n++)
      #pragma unroll
      for (int r=0;r<4;r++)
        Psm[wid][(lh*4+r)*72 + n*16 + lr] = f2bf(s[n][r]);
    // PV
    #pragma unroll
    for (int c=0;c<2;c++){
      bf16x8 pf = *(const bf16x8*)&Psm[wid][lr*72 + c*32 + lh*8];
      #pragma unroll
      for (int dt=0;dt<5;dt++){
        bf16x8 vf = *(const bf16x8*)&Vtsm[(dt*16+lr)*72 + c*32 + lh*8];
        o[dt] = __builtin_amdgcn_mfma_f32_16x16x32_bf16(pf, vf, o[dt], 0,0,0);
      }
    }
    __syncthreads();
  }
  // epilogue: divide by row sum, write bf16 AO[S][DIM]
  #pragma unroll
  for (int r=0;r<4;r++){
    float inv = 1.0f / lsum[r];
    int qrow = q0 + wid*16 + lh*4 + r;
    #pragma unroll
    for (int dt=0;dt<5;dt++)
      AO[(size_t)qrow*DIM + h*HD + dt*16 + lr] = f2bf(o[dt][r]*inv);
  }
}

extern "C" void kernel_launch(void* const* d_in, const int* in_sizes, int n_in,
                              void* d_out, int out_size, void* d_ws, size_t ws_size,
                              hipStream_t stream){
  const float* hs    = (const float*)d_in[0];
  const float* cosb  = (const float*)d_in[1];
  const float* sinb  = (const float*)d_in[2];
  const float* wqkv  = (const float*)d_in[3];
  const float* bqkv  = (const float*)d_in[4];
  const float* wproj = (const float*)d_in[5];
  const float* bproj = (const float*)d_in[6];
  float* out = (float*)d_out;

  unsigned short* Abf    = (unsigned short*)d_ws;              // [SEQ][DIM] bf16
  unsigned short* Wqkvb  = Abf + (size_t)SEQ*DIM;              // [3*DIM][DIM] bf16
  unsigned short* Wprojb = Wqkvb + (size_t)3*DIM*DIM;          // [DIM][DIM] bf16
  unsigned short* QKVb   = Wprojb + (size_t)DIM*DIM;           // [3][NH][SEQ][HD] bf16
  unsigned short* Vtb    = QKVb + (size_t)3*SEQ*DIM;           // [NH][HD][SEQ] bf16
  unsigned short* AObf   = Abf;                                // reuse (A dead after gemm1)

  pack_bf16_kernel<<<(SEQ*DIM/4)/256, 256, 0, stream>>>(hs, Abf, SEQ*DIM/4);
  pack_bf16_kernel<<<(3*DIM*DIM/4)/256, 256, 0, stream>>>(wqkv, Wqkvb, 3*DIM*DIM/4);
  pack_bf16_kernel<<<(DIM*DIM/4)/256, 256, 0, stream>>>(wproj, Wprojb, DIM*DIM/4);

  gemm_bt_kernel<0><<<(SEQ/128)*((3*DIM)/128), 256, 0, stream>>>(Abf, Wqkvb, bqkv,
                                                                 (void*)QKVb, SEQ, 3*DIM, DIM);

  rope_kernel<<<(2*NH*SEQ*40)/256, 256, 0, stream>>>(QKVb, cosb, sinb);

  transpose_v_kernel<<<NH*(SEQ/64), 256, 0, stream>>>(QKVb + (size_t)2*NH*SEQ*HD, Vtb);

  attn_kernel<<<NSEG*NH*(SEGL/64), 256, 0, stream>>>(QKVb, Vtb, AObf);

  gemm_bt_kernel<1><<<(SEQ/128)*(DIM/128), 256, 0, stream>>>(AObf, Wprojb, bproj,
                                                             (void*)out, SEQ, DIM, DIM);
}

// Round 4
// 669.673 us; speedup vs baseline: 1.2640x; 1.1193x over previous
//
#include <hip/hip_runtime.h>

#define SEQ 16384
#define DIM 1280
#define NH 16
#define HD 80
#define NSEG 16
#define SEGL 1024

typedef __attribute__((ext_vector_type(8))) short bf16x8;
typedef __attribute__((ext_vector_type(4))) float f32x4;

__device__ inline unsigned short f2bf(float f){
  unsigned int x = __builtin_bit_cast(unsigned int, f);
  unsigned int r = (x + 0x7FFFu + ((x >> 16) & 1u)) >> 16;
  return (unsigned short)r;
}
__device__ inline float bf2f(unsigned short u){
  unsigned int x = ((unsigned int)u) << 16;
  return __builtin_bit_cast(float, x);
}
__device__ inline int cvtpk_bf16(float lo, float hi){
  int r;
  asm("v_cvt_pk_bf16_f32 %0, %1, %2" : "=v"(r) : "v"(lo), "v"(hi));
  return r;
}

__device__ inline void gload16(const unsigned short* g, unsigned short* l){
  __builtin_amdgcn_global_load_lds((const __attribute__((address_space(1))) void*)g,
                                   (__attribute__((address_space(3))) void*)l, 16, 0, 0);
}

// ---------------- pack f32 -> bf16 ----------------
__global__ __launch_bounds__(256) void pack_bf16_kernel(const float* __restrict__ src,
                                                        unsigned short* __restrict__ dst, int n4){
  int i = blockIdx.x * 256 + threadIdx.x;
  if (i >= n4) return;
  float4 v = ((const float4*)src)[i];
  ushort4 o;
  o.x = f2bf(v.x); o.y = f2bf(v.y); o.z = f2bf(v.z); o.w = f2bf(v.w);
  ((ushort4*)dst)[i] = o;
}

// ---------------- GEMM C = A * B^T (+bias), bf16 in, m97-style 128x128 tile ----------------
// EPI==0: scatter bf16 into QKV[3][NH][SEQ][HD]  (N == 3*DIM)
// EPI==1: write f32 row-major [M][N]
template<int EPI>
__global__ __launch_bounds__(256) void gemm_bt_kernel(const unsigned short* __restrict__ A,
    const unsigned short* __restrict__ B, const float* __restrict__ bias,
    void* __restrict__ Cout, int M, int N, int K){
  __shared__ __attribute__((aligned(16))) unsigned short Asm[128*32];
  __shared__ __attribute__((aligned(16))) unsigned short Bsm[128*32];
  int ntiles = N >> 7;
  int bx = blockIdx.x;
  int tm = (bx / ntiles) << 7;
  int tn = (bx % ntiles) << 7;
  int tid = threadIdx.x, wid = tid >> 6, l = tid & 63;
  int lr = l & 15, lh = l >> 4;
  int wr = (wid >> 1) << 6, wc = (wid & 1) << 6;
  int lrow = l >> 2, lk = (l & 3) * 8;
  f32x4 zf = {0.f,0.f,0.f,0.f};
  f32x4 acc[4][4];
  #pragma unroll
  for (int i=0;i<4;i++)
    #pragma unroll
    for (int j=0;j<4;j++) acc[i][j] = zf;
  const unsigned short* Ab = A + (size_t)tm * K;
  const unsigned short* Bb = B + (size_t)tn * K;
  for (int kt = 0; kt < K; kt += 32){
    __syncthreads();
    #pragma unroll
    for (int i=0;i<2;i++){
      int ch = wid*2 + i;
      gload16(Ab + (size_t)(ch*16 + lrow)*K + kt + lk, &Asm[ch*16*32]);
      gload16(Bb + (size_t)(ch*16 + lrow)*K + kt + lk, &Bsm[ch*16*32]);
    }
    __syncthreads();
    bf16x8 af[4], bfr[4];
    #pragma unroll
    for (int mi=0;mi<4;mi++) af[mi] = *(const bf16x8*)&Asm[(wr + mi*16 + lr)*32 + lh*8];
    #pragma unroll
    for (int ni=0;ni<4;ni++) bfr[ni] = *(const bf16x8*)&Bsm[(wc + ni*16 + lr)*32 + lh*8];
    #pragma unroll
    for (int mi=0;mi<4;mi++)
      #pragma unroll
      for (int ni=0;ni<4;ni++)
        acc[mi][ni] = __builtin_amdgcn_mfma_f32_16x16x32_bf16(af[mi], bfr[ni], acc[mi][ni], 0,0,0);
  }
  // epilogue
  #pragma unroll
  for (int ni=0;ni<4;ni++){
    int col = tn + wc + ni*16 + lr;
    float bv = bias[col];
    if (EPI == 0){
      unsigned short* Q = (unsigned short*)Cout;
      int which = col / DIM;
      int rem = col - which*DIM;
      int hh = rem / HD;
      int d = rem - hh*HD;
      size_t base = (size_t)(which*NH + hh) * SEQ;
      #pragma unroll
      for (int mi=0;mi<4;mi++){
        #pragma unroll
        for (int r=0;r<4;r++){
          int row = tm + wr + mi*16 + lh*4 + r;
          Q[(base + row)*HD + d] = f2bf(acc[mi][ni][r] + bv);
        }
      }
    } else {
      float* C = (float*)Cout;
      #pragma unroll
      for (int mi=0;mi<4;mi++){
        #pragma unroll
        for (int r=0;r<4;r++){
          int row = tm + wr + mi*16 + lh*4 + r;
          C[(size_t)row*N + col] = acc[mi][ni][r] + bv;
        }
      }
    }
  }
}

// ---------------- in-place RoPE on Q,K parts of QKV; Q pre-scaled by 1/sqrt(80)*log2(e) ----------------
__global__ __launch_bounds__(256) void rope_kernel(unsigned short* __restrict__ QKV,
    const float* __restrict__ cosb, const float* __restrict__ sinb){
  unsigned int gid = blockIdx.x * 256 + threadIdx.x; // 2*NH*SEQ*40 total
  int pd = gid % 40;
  unsigned int row = gid / 40;       // [(which*NH+h)*SEQ + s]
  int s = row % SEQ;
  float f = (row < (unsigned)(NH*SEQ)) ? (0.111803398874989485f * 1.4426950408889634f) : 1.0f;
  unsigned short* p = QKV + (size_t)row * HD;
  float c  = cosb[s*HD + pd];
  float sn = sinb[s*HD + pd];
  float x1 = bf2f(p[pd]);
  float x2 = bf2f(p[pd+40]);
  p[pd]    = f2bf((x1*c - x2*sn)*f);
  p[pd+40] = f2bf((x2*c + x1*sn)*f);
}

// ---------------- transpose V: [NH][SEQ][HD] -> Vt [NH][HD][SEQ] ----------------
__global__ __launch_bounds__(256) void transpose_v_kernel(const unsigned short* __restrict__ V,
                                                          unsigned short* __restrict__ Vt){
  __shared__ unsigned short L[64*84];
  int bid = blockIdx.x;
  int h  = bid >> 8;           // SEQ/64 = 256 s-tiles
  int st = bid & 255;
  int s0 = st * 64;
  int tid = threadIdx.x;
  const unsigned short* Vs = V + (size_t)h * SEQ * HD;
  #pragma unroll
  for (int i=0;i<3;i++){
    int u = i*256 + tid;
    if (u < 640){
      int r = u / 10, c = u % 10;
      uint4 v = *(const uint4*)(Vs + (size_t)(s0 + r)*HD + c*8);
      unsigned int* p = (unsigned int*)&L[r*84 + c*8];
      p[0] = v.x; p[1] = v.y; p[2] = v.z; p[3] = v.w;
    }
  }
  __syncthreads();
  unsigned short* Vd = Vt + (size_t)h * HD * SEQ;
  #pragma unroll
  for (int i=0;i<5;i++){
    int u = i*256 + tid;      // 1280 units
    int d = u >> 4, g = u & 15;
    int sb = g*4;
    unsigned int w0 = (unsigned int)L[(sb+0)*84 + d] | ((unsigned int)L[(sb+1)*84 + d] << 16);
    unsigned int w1 = (unsigned int)L[(sb+2)*84 + d] | ((unsigned int)L[(sb+3)*84 + d] << 16);
    uint2 o = {w0, w1};
    *(uint2*)(Vd + (size_t)d*SEQ + s0 + sb) = o;
  }
}

// ---------------- flash attention, swapped operands: lane owns ONE q-row ----------------
// S = mfma(K, Q^T)  -> C[key, q]  (col=q=lr, key-slot = n*16 + lh*4 + r)
// O = mfma(V^T, P^T)-> C[d, q]    (col=q=lr, d = dt*16 + lh*4 + r)
// Vtsm columns are PERMUTED so the PV B-frag is lane-local:
//   PV k-slot (lh*8+j) within a 32-chunk  <->  key-slot ((j>>2)*16 + lh*4 + (j&3))
__global__ __launch_bounds__(256) void attn_kernel(const unsigned short* __restrict__ QKV,
                                                   const unsigned short* __restrict__ Vt,
                                                   unsigned short* __restrict__ AO){
  int bid = blockIdx.x;
  int qt  = bid & 15;
  int h   = (bid >> 4) & 15;
  int seg = bid >> 8;
  int tid = threadIdx.x, wid = tid >> 6, l = tid & 63;
  int lr = l & 15, lh = l >> 4;
  const unsigned short* Qb = QKV + (size_t)(0*NH + h) * SEQ * HD;
  const unsigned short* Kb = QKV + (size_t)(1*NH + h) * SEQ * HD;
  const unsigned short* Vtb = Vt + (size_t)h * HD * SEQ;
  int q0 = seg*SEGL + qt*64;
  __shared__ __attribute__((aligned(16))) unsigned short Ksm[64*104];
  __shared__ __attribute__((aligned(16))) unsigned short Vtsm[80*72];
  bf16x8 qf[3];
  {
    const unsigned short* qp = Qb + (size_t)(q0 + wid*16 + lr) * HD;
    #pragma unroll
    for (int c=0;c<3;c++){
      int d0 = c*32 + lh*8;
      bf16x8 z = {0,0,0,0,0,0,0,0};
      qf[c] = (d0 < HD) ? *(const bf16x8*)(qp + d0) : z;
    }
  }
  f32x4 zf = {0.f,0.f,0.f,0.f};
  f32x4 o[5];
  #pragma unroll
  for (int dt=0;dt<5;dt++) o[dt] = zf;
  float m = -1e30f, lsum = 0.f;
  for (int kt=0; kt<16; kt++){
    int k0 = seg*SEGL + kt*64;
    // stage K tile [64][104] (d 80..95 zeroed for padded MFMA chunk)
    #pragma unroll
    for (int i=0;i<3;i++){
      int u = tid + 256*i;      // 768 units
      int row = u / 12, c = u % 12;
      uint4 val = {0,0,0,0};
      if (c < 10) val = *(const uint4*)(Kb + (size_t)(k0+row)*HD + c*8);
      *(uint4*)&Ksm[row*104 + c*8] = val;
    }
    // stage V^T tile [80][72] with permuted columns:
    // 4-short seq-group t (0..15) -> col 32*(t>>3) + 4*(((t&3)<<1)|((t>>2)&1))
    #pragma unroll
    for (int i=0;i<3;i++){
      int u = tid + 256*i;      // 640 units
      if (u < 640){
        int d = u >> 3, c = u & 7;
        uint4 v = *(const uint4*)(Vtb + (size_t)d*SEQ + k0 + c*8);
        int t0 = 2*c, t1 = 2*c+1;
        int col0 = ((t0>>3)<<5) + ((((t0&3)<<1)|((t0>>2)&1))<<2);
        int col1 = ((t1>>3)<<5) + ((((t1&3)<<1)|((t1>>2)&1))<<2);
        uint2 lo = {v.x, v.y}, hi = {v.z, v.w};
        *(uint2*)&Vtsm[d*72 + col0] = lo;
        *(uint2*)&Vtsm[d*72 + col1] = hi;
      }
    }
    __syncthreads();
    // S = K . Q^T (Q pre-scaled by 1/sqrt(80)*log2e in rope)
    f32x4 s[4];
    #pragma unroll
    for (int n=0;n<4;n++) s[n] = zf;
    #pragma unroll
    for (int c=0;c<3;c++){
      #pragma unroll
      for (int n=0;n<4;n++){
        bf16x8 kf = *(const bf16x8*)&Ksm[(n*16+lr)*104 + c*32 + lh*8];
        s[n] = __builtin_amdgcn_mfma_f32_16x16x32_bf16(kf, qf[c], s[n], 0,0,0);
      }
    }
    // online softmax in base-2; lane owns q-row lr, 16 of 64 keys
    float mx = s[0][0];
    #pragma unroll
    for (int n=0;n<4;n++)
      #pragma unroll
      for (int r=0;r<4;r++) mx = fmaxf(mx, s[n][r]);
    mx = fmaxf(mx, __shfl_xor(mx, 16));
    mx = fmaxf(mx, __shfl_xor(mx, 32));
    float mn = fmaxf(m, mx);
    float corr = exp2f(m - mn);
    m = mn;
    float rs = 0.f;
    #pragma unroll
    for (int n=0;n<4;n++)
      #pragma unroll
      for (int r=0;r<4;r++){
        float p = exp2f(s[n][r] - mn);
        s[n][r] = p;
        rs += p;
      }
    rs += __shfl_xor(rs, 16);
    rs += __shfl_xor(rs, 32);
    lsum = lsum*corr + rs;
    #pragma unroll
    for (int dt=0;dt<5;dt++)
      #pragma unroll
      for (int r=0;r<4;r++) o[dt][r] *= corr;
    // pack P rows to bf16 pairs: w[2n] = keys {n*16+lh*4+0,+1}, w[2n+1] = {+2,+3}
    int w[8];
    #pragma unroll
    for (int n=0;n<4;n++){
      w[2*n]   = cvtpk_bf16(s[n][0], s[n][1]);
      w[2*n+1] = cvtpk_bf16(s[n][2], s[n][3]);
    }
    // PV: B-frag is lane-local thanks to the Vtsm column permutation
    #pragma unroll
    for (int kc=0;kc<2;kc++){
      union { bf16x8 v; int u[4]; } pf;
      pf.u[0] = w[4*kc+0]; pf.u[1] = w[4*kc+1];
      pf.u[2] = w[4*kc+2]; pf.u[3] = w[4*kc+3];
      #pragma unroll
      for (int dt=0;dt<5;dt++){
        bf16x8 vf = *(const bf16x8*)&Vtsm[(dt*16+lr)*72 + kc*32 + lh*8];
        o[dt] = __builtin_amdgcn_mfma_f32_16x16x32_bf16(vf, pf.v, o[dt], 0,0,0);
      }
    }
    __syncthreads();
  }
  // epilogue: lane holds out[q=lr][d = dt*16 + lh*4 + r]
  float inv = 1.0f / lsum;
  int qrow = q0 + wid*16 + lr;
  unsigned short* op = AO + (size_t)qrow*DIM + h*HD;
  #pragma unroll
  for (int dt=0;dt<5;dt++){
    unsigned int w0 = (unsigned int)cvtpk_bf16(o[dt][0]*inv, o[dt][1]*inv);
    unsigned int w1 = (unsigned int)cvtpk_bf16(o[dt][2]*inv, o[dt][3]*inv);
    uint2 ov = {w0, w1};
    *(uint2*)(op + dt*16 + lh*4) = ov;
  }
}

extern "C" void kernel_launch(void* const* d_in, const int* in_sizes, int n_in,
                              void* d_out, int out_size, void* d_ws, size_t ws_size,
                              hipStream_t stream){
  const float* hs    = (const float*)d_in[0];
  const float* cosb  = (const float*)d_in[1];
  const float* sinb  = (const float*)d_in[2];
  const float* wqkv  = (const float*)d_in[3];
  const float* bqkv  = (const float*)d_in[4];
  const float* wproj = (const float*)d_in[5];
  const float* bproj = (const float*)d_in[6];
  float* out = (float*)d_out;

  unsigned short* Abf    = (unsigned short*)d_ws;              // [SEQ][DIM] bf16
  unsigned short* Wqkvb  = Abf + (size_t)SEQ*DIM;              // [3*DIM][DIM] bf16
  unsigned short* Wprojb = Wqkvb + (size_t)3*DIM*DIM;          // [DIM][DIM] bf16
  unsigned short* QKVb   = Wprojb + (size_t)DIM*DIM;           // [3][NH][SEQ][HD] bf16
  unsigned short* Vtb    = QKVb + (size_t)3*SEQ*DIM;           // [NH][HD][SEQ] bf16
  unsigned short* AObf   = Abf;                                // reuse (A dead after gemm1)

  pack_bf16_kernel<<<(SEQ*DIM/4)/256, 256, 0, stream>>>(hs, Abf, SEQ*DIM/4);
  pack_bf16_kernel<<<(3*DIM*DIM/4)/256, 256, 0, stream>>>(wqkv, Wqkvb, 3*DIM*DIM/4);
  pack_bf16_kernel<<<(DIM*DIM/4)/256, 256, 0, stream>>>(wproj, Wprojb, DIM*DIM/4);

  gemm_bt_kernel<0><<<(SEQ/128)*((3*DIM)/128), 256, 0, stream>>>(Abf, Wqkvb, bqkv,
                                                                 (void*)QKVb, SEQ, 3*DIM, DIM);

  rope_kernel<<<(2*NH*SEQ*40)/256, 256, 0, stream>>>(QKVb, cosb, sinb);

  transpose_v_kernel<<<NH*(SEQ/64), 256, 0, stream>>>(QKVb + (size_t)2*NH*SEQ*HD, Vtb);

  attn_kernel<<<NSEG*NH*(SEGL/64), 256, 0, stream>>>(QKVb, Vtb, AObf);

  gemm_bt_kernel<1><<<(SEQ/128)*(DIM/128), 256, 0, stream>>>(AObf, Wprojb, bproj,
                                                             (void*)out, SEQ, DIM, DIM);
}

// Round 5
// 595.092 us; speedup vs baseline: 1.4224x; 1.1253x over previous
//
#include <hip/hip_runtime.h>

#define SEQ 16384
#define DIM 1280
#define NH 16
#define HD 80
#define NSEG 16
#define SEGL 1024

typedef __attribute__((ext_vector_type(8))) short bf16x8;
typedef __attribute__((ext_vector_type(4))) float f32x4;

__device__ inline unsigned short f2bf(float f){
  unsigned int x = __builtin_bit_cast(unsigned int, f);
  unsigned int r = (x + 0x7FFFu + ((x >> 16) & 1u)) >> 16;
  return (unsigned short)r;
}
__device__ inline float bf2f(unsigned short u){
  unsigned int x = ((unsigned int)u) << 16;
  return __builtin_bit_cast(float, x);
}
__device__ inline int cvtpk_bf16(float lo, float hi){
  int r;
  asm("v_cvt_pk_bf16_f32 %0, %1, %2" : "=v"(r) : "v"(lo), "v"(hi));
  return r;
}

__device__ inline void gload16(const unsigned short* g, unsigned short* l){
  __builtin_amdgcn_global_load_lds((const __attribute__((address_space(1))) void*)g,
                                   (__attribute__((address_space(3))) void*)l, 16, 0, 0);
}

// ---------------- pack f32 -> bf16 ----------------
__global__ __launch_bounds__(256) void pack_bf16_kernel(const float* __restrict__ src,
                                                        unsigned short* __restrict__ dst, int n4){
  int i = blockIdx.x * 256 + threadIdx.x;
  if (i >= n4) return;
  float4 v = ((const float4*)src)[i];
  ushort4 o;
  o.x = f2bf(v.x); o.y = f2bf(v.y); o.z = f2bf(v.z); o.w = f2bf(v.w);
  ((ushort4*)dst)[i] = o;
}

// ---------------- 256x256 8-phase GEMM  C = A * B^T (+bias), bf16 in ----------------
// T2 LDS XOR-swizzle (both-sides), T3/T4 counted-vmcnt 4-phase schedule, T5 setprio,
// T1 bijective XCD swizzle. 8 waves (2M x 4N), BK=64, 128 KiB LDS double-buffer.
// EPI==0: scatter bf16 into QKV[3][NH][SEQ][HD]; EPI==1: f32 row-major [M][N].
template<int EPI>
__global__ __launch_bounds__(512, 2) void gemm256_kernel(const unsigned short* __restrict__ A,
    const unsigned short* __restrict__ B, const float* __restrict__ bias,
    void* __restrict__ Cout, int M, int N, int K){
  __shared__ __attribute__((aligned(16))) unsigned short As[2][16384];
  __shared__ __attribute__((aligned(16))) unsigned short Bs[2][16384];
  const int nwg = gridDim.x;
  int bid = blockIdx.x;
  int swz = (bid & 7) * (nwg >> 3) + (bid >> 3);   // nwg % 8 == 0 for our shapes
  const int ntn = N >> 8;
  const int tm = (swz / ntn) << 8;
  const int tn = (swz % ntn) << 8;
  const int tid = threadIdx.x;
  const int wid = tid >> 6, l = tid & 63;
  const int lr = l & 15, lh = l >> 4;
  const int wrM = (wid >> 2) << 7;   // 0 / 128
  const int wcN = (wid & 3) << 6;    // 0 / 64 / 128 / 192
  const int NT = K >> 6;

  // staging constants: chunk c = q*512 + wid*64 + l; row = c>>3, phys colbyte = (c&7)*16
  // swizzle: phys (r,cb) holds logical (r, cb ^ ((r&7)<<4)) -> source col pre-XOR'd
  const int srow = wid*8 + (l >> 3);              // + q*64 + h*128
  const int scol = ((l & 7) ^ (l >> 3)) << 3;     // shorts
  const int sldsu = wid << 9;                     // shorts; + q*4096 + h*8192

  const unsigned short* Ag = A + (size_t)tm * K;
  const unsigned short* Bg = B + (size_t)tn * K;

  // frag-read constants: phys shorts = row*64 + ((ks*32 + lh*8) ^ ((row&7)<<3)), row&7 == l&7
  const int ck0 = (lh*8) ^ ((l & 7) << 3);
  const int ck1 = (32 + lh*8) ^ ((l & 7) << 3);
  const int raA = (wrM + lr) << 6;
  const int raB = (wcN + lr) << 6;

  f32x4 zf = {0.f,0.f,0.f,0.f};
  f32x4 acc[8][4];
  #pragma unroll
  for (int i=0;i<8;i++)
    #pragma unroll
    for (int j=0;j<4;j++) acc[i][j] = zf;

  // prologue: stage all 4 half-tiles of K-tile 0 into buffer 0 (8 loads/thread)
  #pragma unroll
  for (int h=0; h<2; h++)
    #pragma unroll
    for (int q=0; q<2; q++){
      gload16(Ag + (size_t)(h*128 + q*64 + srow)*K + scol, &As[0][h*8192 + q*4096 + sldsu]);
      gload16(Bg + (size_t)(h*128 + q*64 + srow)*K + scol, &Bs[0][h*8192 + q*4096 + sldsu]);
    }

  int cur = 0;
  for (int t = 0; t < NT; ++t){
    const int kt1 = (t+1) << 6;
    const bool more = (t+1 < NT);
    bf16x8 a[2][4], bx[2][2], by[2][2];

    // ---- phase 0: stage A-h0(t+1); counted vmcnt; barrier; read a(m0..3)+bx(n0,1); MFMA
    if (more){
      #pragma unroll
      for (int q=0;q<2;q++)
        gload16(Ag + (size_t)(q*64 + srow)*K + kt1 + scol, &As[cur^1][q*4096 + sldsu]);
      asm volatile("s_waitcnt vmcnt(2)" ::: "memory");
    } else {
      asm volatile("s_waitcnt vmcnt(0)" ::: "memory");
    }
    __builtin_amdgcn_s_barrier();
    #pragma unroll
    for (int mi=0;mi<4;mi++){
      a[0][mi] = *(const bf16x8*)&As[cur][raA + mi*1024 + ck0];
      a[1][mi] = *(const bf16x8*)&As[cur][raA + mi*1024 + ck1];
    }
    #pragma unroll
    for (int nj=0;nj<2;nj++){
      bx[0][nj] = *(const bf16x8*)&Bs[cur][raB + nj*1024 + ck0];
      bx[1][nj] = *(const bf16x8*)&Bs[cur][raB + nj*1024 + ck1];
    }
    __builtin_amdgcn_s_setprio(1);
    #pragma unroll
    for (int mi=0;mi<4;mi++)
      #pragma unroll
      for (int nj=0;nj<2;nj++){
        acc[mi][nj] = __builtin_amdgcn_mfma_f32_16x16x32_bf16(a[0][mi], bx[0][nj], acc[mi][nj], 0,0,0);
        acc[mi][nj] = __builtin_amdgcn_mfma_f32_16x16x32_bf16(a[1][mi], bx[1][nj], acc[mi][nj], 0,0,0);
      }
    __builtin_amdgcn_s_setprio(0);
    __builtin_amdgcn_s_barrier();

    // ---- phase 1: read by(n2,3); stage A-h1(t+1); barrier; MFMA m0..3 x n2,3
    #pragma unroll
    for (int nj=0;nj<2;nj++){
      by[0][nj] = *(const bf16x8*)&Bs[cur][raB + (nj+2)*1024 + ck0];
      by[1][nj] = *(const bf16x8*)&Bs[cur][raB + (nj+2)*1024 + ck1];
    }
    if (more){
      #pragma unroll
      for (int q=0;q<2;q++)
        gload16(Ag + (size_t)(128 + q*64 + srow)*K + kt1 + scol, &As[cur^1][8192 + q*4096 + sldsu]);
    }
    __builtin_amdgcn_s_barrier();
    __builtin_amdgcn_s_setprio(1);
    #pragma unroll
    for (int mi=0;mi<4;mi++)
      #pragma unroll
      for (int nj=0;nj<2;nj++){
        acc[mi][nj+2] = __builtin_amdgcn_mfma_f32_16x16x32_bf16(a[0][mi], by[0][nj], acc[mi][nj+2], 0,0,0);
        acc[mi][nj+2] = __builtin_amdgcn_mfma_f32_16x16x32_bf16(a[1][mi], by[1][nj], acc[mi][nj+2], 0,0,0);
      }
    __builtin_amdgcn_s_setprio(0);
    __builtin_amdgcn_s_barrier();

    // ---- phase 2: read a(m4..7); stage B-h0(t+1); barrier; MFMA m4..7 x n2,3
    #pragma unroll
    for (int mi=0;mi<4;mi++){
      a[0][mi] = *(const bf16x8*)&As[cur][raA + (mi+4)*1024 + ck0];
      a[1][mi] = *(const bf16x8*)&As[cur][raA + (mi+4)*1024 + ck1];
    }
    if (more){
      #pragma unroll
      for (int q=0;q<2;q++)
        gload16(Bg + (size_t)(q*64 + srow)*K + kt1 + scol, &Bs[cur^1][q*4096 + sldsu]);
    }
    __builtin_amdgcn_s_barrier();
    __builtin_amdgcn_s_setprio(1);
    #pragma unroll
    for (int mi=0;mi<4;mi++)
      #pragma unroll
      for (int nj=0;nj<2;nj++){
        acc[mi+4][nj+2] = __builtin_amdgcn_mfma_f32_16x16x32_bf16(a[0][mi], by[0][nj], acc[mi+4][nj+2], 0,0,0);
        acc[mi+4][nj+2] = __builtin_amdgcn_mfma_f32_16x16x32_bf16(a[1][mi], by[1][nj], acc[mi+4][nj+2], 0,0,0);
      }
    __builtin_amdgcn_s_setprio(0);
    __builtin_amdgcn_s_barrier();

    // ---- phase 3: reload bx(n0,1); stage B-h1(t+1); barrier; MFMA m4..7 x n0,1
    #pragma unroll
    for (int nj=0;nj<2;nj++){
      bx[0][nj] = *(const bf16x8*)&Bs[cur][raB + nj*1024 + ck0];
      bx[1][nj] = *(const bf16x8*)&Bs[cur][raB + nj*1024 + ck1];
    }
    if (more){
      #pragma unroll
      for (int q=0;q<2;q++)
        gload16(Bg + (size_t)(128 + q*64 + srow)*K + kt1 + scol, &Bs[cur^1][8192 + q*4096 + sldsu]);
    }
    __builtin_amdgcn_s_barrier();
    __builtin_amdgcn_s_setprio(1);
    #pragma unroll
    for (int mi=0;mi<4;mi++)
      #pragma unroll
      for (int nj=0;nj<2;nj++){
        acc[mi+4][nj] = __builtin_amdgcn_mfma_f32_16x16x32_bf16(a[0][mi], bx[0][nj], acc[mi+4][nj], 0,0,0);
        acc[mi+4][nj] = __builtin_amdgcn_mfma_f32_16x16x32_bf16(a[1][mi], bx[1][nj], acc[mi+4][nj], 0,0,0);
      }
    __builtin_amdgcn_s_setprio(0);
    __builtin_amdgcn_s_barrier();

    cur ^= 1;
  }

  // epilogue
  #pragma unroll
  for (int nj=0;nj<4;nj++){
    int col = tn + wcN + nj*16 + lr;
    float bv = bias[col];
    if (EPI == 0){
      unsigned short* Q = (unsigned short*)Cout;
      int which = col / DIM;
      int rem = col - which*DIM;
      int hh = rem / HD;
      int d = rem - hh*HD;
      size_t base = (size_t)(which*NH + hh) * SEQ;
      #pragma unroll
      for (int mi=0;mi<8;mi++){
        #pragma unroll
        for (int r=0;r<4;r++){
          int row = tm + wrM + mi*16 + lh*4 + r;
          Q[(base + row)*HD + d] = f2bf(acc[mi][nj][r] + bv);
        }
      }
    } else {
      float* C = (float*)Cout;
      #pragma unroll
      for (int mi=0;mi<8;mi++){
        #pragma unroll
        for (int r=0;r<4;r++){
          int row = tm + wrM + mi*16 + lh*4 + r;
          C[(size_t)row*N + col] = acc[mi][nj][r] + bv;
        }
      }
    }
  }
}

// ---------------- in-place RoPE on Q,K parts of QKV; Q pre-scaled by 1/sqrt(80)*log2(e) ----------------
__global__ __launch_bounds__(256) void rope_kernel(unsigned short* __restrict__ QKV,
    const float* __restrict__ cosb, const float* __restrict__ sinb){
  unsigned int gid = blockIdx.x * 256 + threadIdx.x; // 2*NH*SEQ*40 total
  int pd = gid % 40;
  unsigned int row = gid / 40;       // [(which*NH+h)*SEQ + s]
  int s = row % SEQ;
  float f = (row < (unsigned)(NH*SEQ)) ? (0.111803398874989485f * 1.4426950408889634f) : 1.0f;
  unsigned short* p = QKV + (size_t)row * HD;
  float c  = cosb[s*HD + pd];
  float sn = sinb[s*HD + pd];
  float x1 = bf2f(p[pd]);
  float x2 = bf2f(p[pd+40]);
  p[pd]    = f2bf((x1*c - x2*sn)*f);
  p[pd+40] = f2bf((x2*c + x1*sn)*f);
}

// ---------------- transpose V: [NH][SEQ][HD] -> Vt [NH][HD][SEQ] ----------------
__global__ __launch_bounds__(256) void transpose_v_kernel(const unsigned short* __restrict__ V,
                                                          unsigned short* __restrict__ Vt){
  __shared__ unsigned short L[64*84];
  int bid = blockIdx.x;
  int h  = bid >> 8;           // SEQ/64 = 256 s-tiles
  int st = bid & 255;
  int s0 = st * 64;
  int tid = threadIdx.x;
  const unsigned short* Vs = V + (size_t)h * SEQ * HD;
  #pragma unroll
  for (int i=0;i<3;i++){
    int u = i*256 + tid;
    if (u < 640){
      int r = u / 10, c = u % 10;
      uint4 v = *(const uint4*)(Vs + (size_t)(s0 + r)*HD + c*8);
      unsigned int* p = (unsigned int*)&L[r*84 + c*8];
      p[0] = v.x; p[1] = v.y; p[2] = v.z; p[3] = v.w;
    }
  }
  __syncthreads();
  unsigned short* Vd = Vt + (size_t)h * HD * SEQ;
  #pragma unroll
  for (int i=0;i<5;i++){
    int u = i*256 + tid;      // 1280 units
    int d = u >> 4, g = u & 15;
    int sb = g*4;
    unsigned int w0 = (unsigned int)L[(sb+0)*84 + d] | ((unsigned int)L[(sb+1)*84 + d] << 16);
    unsigned int w1 = (unsigned int)L[(sb+2)*84 + d] | ((unsigned int)L[(sb+3)*84 + d] << 16);
    uint2 o = {w0, w1};
    *(uint2*)(Vd + (size_t)d*SEQ + s0 + sb) = o;
  }
}

// ---------------- flash attention, swapped operands: lane owns ONE q-row ----------------
// S = mfma(K, Q^T)  -> C[key, q]  (col=q=lr, key-slot = n*16 + lh*4 + r)
// O = mfma(V^T, P^T)-> C[d, q]    (col=q=lr, d = dt*16 + lh*4 + r)
// Vtsm columns are PERMUTED so the PV B-frag is lane-local:
//   PV k-slot (lh*8+j) within a 32-chunk  <->  key-slot ((j>>2)*16 + lh*4 + (j&3))
__global__ __launch_bounds__(256) void attn_kernel(const unsigned short* __restrict__ QKV,
                                                   const unsigned short* __restrict__ Vt,
                                                   unsigned short* __restrict__ AO){
  int bid = blockIdx.x;
  int qt  = bid & 15;
  int h   = (bid >> 4) & 15;
  int seg = bid >> 8;
  int tid = threadIdx.x, wid = tid >> 6, l = tid & 63;
  int lr = l & 15, lh = l >> 4;
  const unsigned short* Qb = QKV + (size_t)(0*NH + h) * SEQ * HD;
  const unsigned short* Kb = QKV + (size_t)(1*NH + h) * SEQ * HD;
  const unsigned short* Vtb = Vt + (size_t)h * HD * SEQ;
  int q0 = seg*SEGL + qt*64;
  __shared__ __attribute__((aligned(16))) unsigned short Ksm[64*104];
  __shared__ __attribute__((aligned(16))) unsigned short Vtsm[80*72];
  bf16x8 qf[3];
  {
    const unsigned short* qp = Qb + (size_t)(q0 + wid*16 + lr) * HD;
    #pragma unroll
    for (int c=0;c<3;c++){
      int d0 = c*32 + lh*8;
      bf16x8 z = {0,0,0,0,0,0,0,0};
      qf[c] = (d0 < HD) ? *(const bf16x8*)(qp + d0) : z;
    }
  }
  f32x4 zf = {0.f,0.f,0.f,0.f};
  f32x4 o[5];
  #pragma unroll
  for (int dt=0;dt<5;dt++) o[dt] = zf;
  float m = -1e30f, lsum = 0.f;
  for (int kt=0; kt<16; kt++){
    int k0 = seg*SEGL + kt*64;
    // stage K tile [64][104] (d 80..95 zeroed for padded MFMA chunk)
    #pragma unroll
    for (int i=0;i<3;i++){
      int u = tid + 256*i;      // 768 units
      int row = u / 12, c = u % 12;
      uint4 val = {0,0,0,0};
      if (c < 10) val = *(const uint4*)(Kb + (size_t)(k0+row)*HD + c*8);
      *(uint4*)&Ksm[row*104 + c*8] = val;
    }
    // stage V^T tile [80][72] with permuted columns:
    // 4-short seq-group t (0..15) -> col 32*(t>>3) + 4*(((t&3)<<1)|((t>>2)&1))
    #pragma unroll
    for (int i=0;i<3;i++){
      int u = tid + 256*i;      // 640 units
      if (u < 640){
        int d = u >> 3, c = u & 7;
        uint4 v = *(const uint4*)(Vtb + (size_t)d*SEQ + k0 + c*8);
        int t0 = 2*c, t1 = 2*c+1;
        int col0 = ((t0>>3)<<5) + ((((t0&3)<<1)|((t0>>2)&1))<<2);
        int col1 = ((t1>>3)<<5) + ((((t1&3)<<1)|((t1>>2)&1))<<2);
        uint2 lo = {v.x, v.y}, hi = {v.z, v.w};
        *(uint2*)&Vtsm[d*72 + col0] = lo;
        *(uint2*)&Vtsm[d*72 + col1] = hi;
      }
    }
    __syncthreads();
    // S = K . Q^T (Q pre-scaled by 1/sqrt(80)*log2e in rope)
    f32x4 s[4];
    #pragma unroll
    for (int n=0;n<4;n++) s[n] = zf;
    #pragma unroll
    for (int c=0;c<3;c++){
      #pragma unroll
      for (int n=0;n<4;n++){
        bf16x8 kf = *(const bf16x8*)&Ksm[(n*16+lr)*104 + c*32 + lh*8];
        s[n] = __builtin_amdgcn_mfma_f32_16x16x32_bf16(kf, qf[c], s[n], 0,0,0);
      }
    }
    // online softmax in base-2; lane owns q-row lr, 16 of 64 keys
    float mx = s[0][0];
    #pragma unroll
    for (int n=0;n<4;n++)
      #pragma unroll
      for (int r=0;r<4;r++) mx = fmaxf(mx, s[n][r]);
    mx = fmaxf(mx, __shfl_xor(mx, 16));
    mx = fmaxf(mx, __shfl_xor(mx, 32));
    float mn = fmaxf(m, mx);
    float corr = exp2f(m - mn);
    m = mn;
    float rs = 0.f;
    #pragma unroll
    for (int n=0;n<4;n++)
      #pragma unroll
      for (int r=0;r<4;r++){
        float p = exp2f(s[n][r] - mn);
        s[n][r] = p;
        rs += p;
      }
    rs += __shfl_xor(rs, 16);
    rs += __shfl_xor(rs, 32);
    lsum = lsum*corr + rs;
    #pragma unroll
    for (int dt=0;dt<5;dt++)
      #pragma unroll
      for (int r=0;r<4;r++) o[dt][r] *= corr;
    // pack P rows to bf16 pairs: w[2n] = keys {n*16+lh*4+0,+1}, w[2n+1] = {+2,+3}
    int w[8];
    #pragma unroll
    for (int n=0;n<4;n++){
      w[2*n]   = cvtpk_bf16(s[n][0], s[n][1]);
      w[2*n+1] = cvtpk_bf16(s[n][2], s[n][3]);
    }
    // PV: B-frag is lane-local thanks to the Vtsm column permutation
    #pragma unroll
    for (int kc=0;kc<2;kc++){
      union { bf16x8 v; int u[4]; } pf;
      pf.u[0] = w[4*kc+0]; pf.u[1] = w[4*kc+1];
      pf.u[2] = w[4*kc+2]; pf.u[3] = w[4*kc+3];
      #pragma unroll
      for (int dt=0;dt<5;dt++){
        bf16x8 vf = *(const bf16x8*)&Vtsm[(dt*16+lr)*72 + kc*32 + lh*8];
        o[dt] = __builtin_amdgcn_mfma_f32_16x16x32_bf16(vf, pf.v, o[dt], 0,0,0);
      }
    }
    __syncthreads();
  }
  // epilogue: lane holds out[q=lr][d = dt*16 + lh*4 + r]
  float inv = 1.0f / lsum;
  int qrow = q0 + wid*16 + lr;
  unsigned short* op = AO + (size_t)qrow*DIM + h*HD;
  #pragma unroll
  for (int dt=0;dt<5;dt++){
    unsigned int w0 = (unsigned int)cvtpk_bf16(o[dt][0]*inv, o[dt][1]*inv);
    unsigned int w1 = (unsigned int)cvtpk_bf16(o[dt][2]*inv, o[dt][3]*inv);
    uint2 ov = {w0, w1};
    *(uint2*)(op + dt*16 + lh*4) = ov;
  }
}

extern "C" void kernel_launch(void* const* d_in, const int* in_sizes, int n_in,
                              void* d_out, int out_size, void* d_ws, size_t ws_size,
                              hipStream_t stream){
  const float* hs    = (const float*)d_in[0];
  const float* cosb  = (const float*)d_in[1];
  const float* sinb  = (const float*)d_in[2];
  const float* wqkv  = (const float*)d_in[3];
  const float* bqkv  = (const float*)d_in[4];
  const float* wproj = (const float*)d_in[5];
  const float* bproj = (const float*)d_in[6];
  float* out = (float*)d_out;

  unsigned short* Abf    = (unsigned short*)d_ws;              // [SEQ][DIM] bf16
  unsigned short* Wqkvb  = Abf + (size_t)SEQ*DIM;              // [3*DIM][DIM] bf16
  unsigned short* Wprojb = Wqkvb + (size_t)3*DIM*DIM;          // [DIM][DIM] bf16
  unsigned short* QKVb   = Wprojb + (size_t)DIM*DIM;           // [3][NH][SEQ][HD] bf16
  unsigned short* Vtb    = QKVb + (size_t)3*SEQ*DIM;           // [NH][HD][SEQ] bf16
  unsigned short* AObf   = Abf;                                // reuse (A dead after gemm1)

  pack_bf16_kernel<<<(SEQ*DIM/4)/256, 256, 0, stream>>>(hs, Abf, SEQ*DIM/4);
  pack_bf16_kernel<<<(3*DIM*DIM/4)/256, 256, 0, stream>>>(wqkv, Wqkvb, 3*DIM*DIM/4);
  pack_bf16_kernel<<<(DIM*DIM/4)/256, 256, 0, stream>>>(wproj, Wprojb, DIM*DIM/4);

  gemm256_kernel<0><<<(SEQ/256)*((3*DIM)/256), 512, 0, stream>>>(Abf, Wqkvb, bqkv,
                                                                 (void*)QKVb, SEQ, 3*DIM, DIM);

  rope_kernel<<<(2*NH*SEQ*40)/256, 256, 0, stream>>>(QKVb, cosb, sinb);

  transpose_v_kernel<<<NH*(SEQ/64), 256, 0, stream>>>(QKVb + (size_t)2*NH*SEQ*HD, Vtb);

  attn_kernel<<<NSEG*NH*(SEGL/64), 256, 0, stream>>>(QKVb, Vtb, AObf);

  gemm256_kernel<1><<<(SEQ/256)*(DIM/256), 512, 0, stream>>>(AObf, Wprojb, bproj,
                                                             (void*)out, SEQ, DIM, DIM);
}